// Round 9
// baseline (2068.127 us; speedup 1.0000x reference)
//
#include <hip/hip_runtime.h>
#include <math.h>

typedef __attribute__((ext_vector_type(8))) short bf16x8;
typedef __attribute__((ext_vector_type(4))) float f32x4;

#define BB 64
#define TT 2048
#define RR 256
#define BLK 24
#define NTHR 512
#define HB_PAD 776   // 768 + 8: rows 16B-aligned
#define HW_PAD 288   // var stride 144 dw = 16 mod 32: conflict-free row-packed reads

#define MFMA(a, b, c) __builtin_amdgcn_mfma_f32_16x16x32_bf16((a), (b), (c), 0, 0, 0)

__device__ __forceinline__ unsigned short f2bf(float f) {
    unsigned u = __float_as_uint(f);
    return (unsigned short)((u + 0x7FFFu + ((u >> 16) & 1u)) >> 16);  // RNE
}
__device__ __forceinline__ float bf2f(unsigned short h) {
    return __uint_as_float(((unsigned)h) << 16);
}
__device__ __forceinline__ float fast_tanh(float x) {
    float e = __expf(2.0f * x);
    return 1.0f - 2.0f * __builtin_amdgcn_rcpf(1.0f + e);
}

// ---- Pre-pass: pack tw[tap]*W_fb[tap] into MFMA B-fragment order (bf16) ----
__global__ void pack_weights(const float* __restrict__ W_fb,
                             const float* __restrict__ tapw,
                             unsigned short* __restrict__ bp) {
    int gid = blockIdx.x * 256 + threadIdx.x;
    int l = gid & 63, c = gid >> 6;
    int tap = c >> 7;
    int rem = c & 127;
    int kt = rem >> 4, nt = rem & 15;

    float v0 = tapw[0], v1 = tapw[1], v2 = tapw[2], v3 = tapw[3], v4 = tapw[4];
    float mx = fmaxf(fmaxf(fmaxf(v0, v1), fmaxf(v2, v3)), v4);
    float e0 = expf(v0 - mx), e1 = expf(v1 - mx), e2 = expf(v2 - mx),
          e3 = expf(v3 - mx), e4 = expf(v4 - mx);
    float inv = 1.0f / (e0 + e1 + e2 + e3 + e4);
    float tws[5] = {e0 * inv, e1 * inv, e2 * inv, e3 * inv, e4 * inv};
    float tw = tws[tap];

    int kbase = 32 * kt + 8 * (l >> 4);
    int n = 16 * nt + (l & 15);
    const float* W = W_fb + tap * 65536;
    unsigned short t[8];
#pragma unroll
    for (int j = 0; j < 8; ++j) t[j] = f2bf(tw * W[(kbase + j) * 256 + n]);
    uint4 o;
    o.x = (unsigned)t[0] | ((unsigned)t[1] << 16);
    o.y = (unsigned)t[2] | ((unsigned)t[3] << 16);
    o.z = (unsigned)t[4] | ((unsigned)t[5] << 16);
    o.w = (unsigned)t[6] | ((unsigned)t[7] << 16);
    *(uint4*)(bp + (size_t)(c * 64 + l) * 8) = o;
}

// ---- Main kernel: one WG per batch, 8 waves; wave w owns s in [32w, 32w+32) ----
// R9 changes vs 1877us R6:
//  Software-pipeline far taps 96/168 into the step loop (they only need h <=
//  t0-73, available in global out long before):
//   - staging for block k+1's hbcb[256:768) spread over block k's steps 0-6
//     (read iter u at step u, LDS-write at step u+1; per-step barriers give
//     free write->read ordering vs the ft-GEMM below)
//   - far-GEMM 96/168: 1 ft per step over steps 8..23 (ft = jj), accumulating
//     into block-long-lived registers cf* (24 VGPR); B-frags prefetched 1 step
//     ahead (fpA/fpB)
//   - block boundary now tap24-only: 3 staging iters from hob + 8-ft GEMM that
//     CONTINUES accumulating into cf*, then Gl2 assembly; cf* reset after.
//  Accumulation order changes only commutatively -> absmax unchanged.
__global__ __launch_bounds__(NTHR, 1)
void reservoir_mfma(const float* __restrict__ x,
                    const float* __restrict__ W_in,
                    const float* __restrict__ bias,
                    const unsigned short* __restrict__ bp,
                    float* __restrict__ out)
{
    const int b    = blockIdx.x;
    const int tid  = threadIdx.x;
    const int lane = tid & 63;
    const int w    = tid >> 6;
    const int l15  = lane & 15;
    const int quad = lane >> 4;

    __shared__ float xs[TT];                             // 8 KB
    __shared__ unsigned short hwinb[8][2][HW_PAD];       // 9 KB: h ring, bf16 hi/lo
    __shared__ unsigned short hbcb[BLK][2][HB_PAD];      // 72.8 KB: far history hi/lo
    __shared__ float2 Gl2[BLK][130];                     // 25 KB: far + drive + bias
    __shared__ float hob[BLK][RR];                       // 24 KB: block h output buffer

    for (int i = tid; i < TT; i += NTHR) xs[i] = x[b * TT + i];
    {
        unsigned* hz = (unsigned*)&hwinb[0][0][0];
        for (int i = tid; i < 8 * 2 * HW_PAD / 2; i += NTHR) hz[i] = 0u;
    }

    // Resident B-fragments: tap d=1 (b1) and d=4 (b4).
    const bf16x8* bpv = (const bf16x8*)bp;
    bf16x8 b1[8][2], b4[8][2];
#pragma unroll
    for (int kt = 0; kt < 8; ++kt)
#pragma unroll
        for (int u = 0; u < 2; ++u) {
            int nt = 2 * w + u;
            b1[kt][u] = bpv[((0 * 8 + kt) * 16 + nt) * 64 + lane];
            b4[kt][u] = bpv[((1 * 8 + kt) * 16 + nt) * 64 + lane];
        }

    const int s0g = 32 * w + l15, s1g = s0g + 16;
    const float win0 = W_in[s0g], win1 = W_in[s1g];
    const float bi0 = bias[s0g], bi1 = bias[s1g];
    float hp0 = 0.0f, hp1 = 0.0f;

    const float* outr = out + (size_t)b * TT * RR;
    float*       outw = out + (size_t)b * TT * RR;

    // Row-packed A-operand base pointers:
    const unsigned short* hw1v = &hwinb[0][l15 & 1][0];
    const unsigned short* hw4v = &hwinb[0][(l15 >> 2) & 1][0];
    const unsigned short* fa1  = &hbcb[16 + (l15 & 7)][(l15 >> 3) & 1][0];
    const size_t HWSLOT = 2 * HW_PAD;

    // Packed-write lane mapping: quad -> {hi,lo} x {s0,s1}
    const int varw  = quad >> 1;
    const int s_w   = 32 * w + l15 + ((quad & 1) << 4);
    unsigned short* const hwb = &hwinb[0][0][0];
    const unsigned hw_off = (unsigned)(varw * HW_PAD + s_w);

    const int r0a = l15;
    const int cw0 = 2 * w, cw1 = 2 * w + 1;
    const f32x4 zf = {0.f, 0.f, 0.f, 0.f};

    // Long-lived far accumulators (taps 96/168 pipelined + tap24 at boundary).
    f32x4 cf00a = zf, cf01a = zf, cf00b = zf, cf01b = zf, cf10 = zf, cf11 = zf;
    // Pipeline registers.
    float4 stg = {0.f, 0.f, 0.f, 0.f};
    int stg_j = 0, stg_r = 256;
    bf16x8 fpA, fpB;

    __syncthreads();

    for (int t0 = 0; t0 < TT; t0 += BLK) {
        // ---- boundary: tap24 only ----
        // tap24 B-frag rotation seed (loads overlap the staging below)
        bf16x8 qA = bpv[((16 + 0) * 16 + cw0) * 64 + lane];
        bf16x8 qB = bpv[((16 + 0) * 16 + cw1) * 64 + lane];
        // stage tap24 rows from previous block's hob (LDS)
#pragma unroll
        for (int it = 0; it < 3; ++it) {                  // 3*512 = 1536 = 24*256/4
            int i = it * NTHR + tid;
            int j = i >> 6;
            int p = i & 63;
            int r = 4 * p;                                 // [0,256)
            float4 v = {0.f, 0.f, 0.f, 0.f};
            if (t0 > 0) v = *(const float4*)&hob[j][r];
            unsigned short h0 = f2bf(v.x), h1 = f2bf(v.y), h2 = f2bf(v.z), h3 = f2bf(v.w);
            unsigned short q0 = f2bf(v.x - bf2f(h0)), q1 = f2bf(v.y - bf2f(h1)),
                           q2 = f2bf(v.z - bf2f(h2)), q3 = f2bf(v.w - bf2f(h3));
            uint2 H = { (unsigned)h0 | ((unsigned)h1 << 16), (unsigned)h2 | ((unsigned)h3 << 16) };
            uint2 Q = { (unsigned)q0 | ((unsigned)q1 << 16), (unsigned)q2 | ((unsigned)q3 << 16) };
            *(uint2*)&hbcb[j][0][r] = H;
            *(uint2*)&hbcb[j][1][r] = Q;
        }
        __syncthreads();

        // tap24 GEMM: ft = 0..7, ro in [0,256); accumulate into cf* (which holds
        // this block's 96/168 partials from the previous block's pipeline).
#pragma unroll 1
        for (int ft = 0; ft < 8; ++ft) {
            bf16x8 B0 = qA, B1 = qB;
            int nf = (ft < 7) ? ft + 1 : 7;
            qA = bpv[((16 + nf) * 16 + cw0) * 64 + lane];
            qB = bpv[((16 + nf) * 16 + cw1) * 64 + lane];
            int ro = 32 * ft + 8 * quad;
            bf16x8 a00 = *(const bf16x8*)&hbcb[r0a][0][ro];
            bf16x8 a01 = *(const bf16x8*)&hbcb[r0a][1][ro];
            bf16x8 a1  = *(const bf16x8*)&fa1[ro];
            cf00a = MFMA(a00, B0, cf00a); cf01a = MFMA(a00, B1, cf01a);
            cf00b = MFMA(a01, B0, cf00b); cf01b = MFMA(a01, B1, cf01b);
            cf10  = MFMA(a1,  B0, cf10);  cf11  = MFMA(a1,  B1, cf11);
        }
        {
            f32x4 cf00 = cf00a + cf00b, cf01 = cf01a + cf01b;
            float cf10f[4], cf11f[4];
#pragma unroll
            for (int i = 0; i < 4; ++i) {
                cf10f[i] = cf10[i] + __shfl_xor(cf10[i], 32, 64);
                cf11f[i] = cf11[i] + __shfl_xor(cf11[i], 32, 64);
            }
#pragma unroll
            for (int i = 0; i < 4; ++i) {
                int j0 = 4 * quad + i;
                int tx0 = t0 + j0; float xv0 = xs[tx0 < TT ? tx0 : TT - 1];
                Gl2[j0][16 * w + l15] =
                    make_float2(cf00[i] + bi0 + xv0 * win0, cf01[i] + bi1 + xv0 * win1);
                int j1 = 16 + 4 * quad + i;
                if (j1 < BLK) {
                    int tx1 = t0 + j1; float xv1 = xs[tx1 < TT ? tx1 : TT - 1];
                    Gl2[j1][16 * w + l15] =
                        make_float2(cf10f[i] + bi0 + xv1 * win0, cf11f[i] + bi1 + xv1 * win1);
                }
            }
            // reset for next block's pipelined accumulation
            cf00a = zf; cf01a = zf; cf00b = zf; cf01b = zf; cf10 = zf; cf11 = zf;
        }
        __syncthreads();

        // ---- sequential sub-blocks of 4 steps, with embedded far pipeline ----
        const int tend = (t0 + BLK < TT) ? (t0 + BLK) : TT;
#pragma unroll 1
        for (int t4 = t0; t4 < tend; t4 += 4) {
            // tap d=4, row-packed
            f32x4 c40 = zf, c41 = zf;
            const int sl = (t4 - 4 + (l15 & 3)) & 7;
            const unsigned short* hw4 = hw4v + (size_t)sl * HWSLOT;
#pragma unroll
            for (int kt = 0; kt < 8; ++kt) {
                int ro = 32 * kt + 8 * quad;
                bf16x8 a = *(const bf16x8*)&hw4[ro];
                c40 = MFMA(a, b4[kt][0], c40);
                c41 = MFMA(a, b4[kt][1], c41);
            }
            float c40f[4], c41f[4];
#pragma unroll
            for (int u2 = 0; u2 < 4; ++u2) {
                c40f[u2] = c40[u2] + __shfl_xor(c40[u2], 16, 64);
                c41f[u2] = c41[u2] + __shfl_xor(c41[u2], 16, 64);
            }
#pragma unroll
            for (int u = 0; u < 4; ++u) {
                const int t = t4 + u;
                const int jj = t - t0;
                const int sp = (t - 1) & 7;
                const unsigned short* hw1 = hw1v + (size_t)sp * HWSLOT;
                f32x4 c10 = zf, c11 = zf;
#pragma unroll
                for (int kt = 0; kt < 8; ++kt) {
                    int ro = 32 * kt + 8 * quad;
                    bf16x8 a = *(const bf16x8*)&hw1[ro];
                    c10 = MFMA(a, b1[kt][0], c10);
                    c11 = MFMA(a, b1[kt][1], c11);
                }

                // ---- far pipeline slice (wave-uniform guards on jj) ----
                if (jj >= 1 && jj <= 6) {
                    // LDS-write staging iter jj-1 (held in stg/stg_j/stg_r)
                    unsigned short h0 = f2bf(stg.x), h1 = f2bf(stg.y),
                                   h2 = f2bf(stg.z), h3 = f2bf(stg.w);
                    unsigned short q0 = f2bf(stg.x - bf2f(h0)), q1 = f2bf(stg.y - bf2f(h1)),
                                   q2 = f2bf(stg.z - bf2f(h2)), q3 = f2bf(stg.w - bf2f(h3));
                    uint2 H = { (unsigned)h0 | ((unsigned)h1 << 16),
                                (unsigned)h2 | ((unsigned)h3 << 16) };
                    uint2 Q = { (unsigned)q0 | ((unsigned)q1 << 16),
                                (unsigned)q2 | ((unsigned)q3 << 16) };
                    *(uint2*)&hbcb[stg_j][0][stg_r] = H;
                    *(uint2*)&hbcb[stg_j][1][stg_r] = Q;
                }
                if (jj < 6) {
                    // issue global read for staging iter jj (for NEXT block t0+BLK)
                    int i2 = jj * NTHR + tid;
                    stg_j = i2 >> 7;
                    int p2 = i2 & 127;
                    stg_r = 256 + 4 * p2;                  // [256,768)
                    int kf = stg_r >> 8;                    // 1 or 2
                    int dk = (kf == 1) ? 96 : 168;
                    int rr = stg_r & 255;
                    int tt = t0 + BLK + stg_j - dk;
                    float4 v = {0.f, 0.f, 0.f, 0.f};
                    if (tt >= 0) v = *(const float4*)(outr + (size_t)tt * RR + rr);
                    stg = v;
                }
                if (jj == 7) {
                    fpA = bpv[((16 + 8) * 16 + cw0) * 64 + lane];
                    fpB = bpv[((16 + 8) * 16 + cw1) * 64 + lane];
                }
                if (jj >= 8) {
                    // far-GEMM slice: ft = jj (96/168 region), for NEXT block
                    bf16x8 B0 = fpA, B1 = fpB;
                    if (jj < 23) {
                        fpA = bpv[((16 + jj + 1) * 16 + cw0) * 64 + lane];
                        fpB = bpv[((16 + jj + 1) * 16 + cw1) * 64 + lane];
                    }
                    int ro = 32 * jj + 8 * quad;
                    bf16x8 a00 = *(const bf16x8*)&hbcb[r0a][0][ro];
                    bf16x8 a01 = *(const bf16x8*)&hbcb[r0a][1][ro];
                    bf16x8 a1  = *(const bf16x8*)&fa1[ro];
                    cf00a = MFMA(a00, B0, cf00a); cf01a = MFMA(a00, B1, cf01a);
                    cf00b = MFMA(a01, B0, cf00b); cf01b = MFMA(a01, B1, cf01b);
                    cf10  = MFMA(a1,  B0, cf10);  cf11  = MFMA(a1,  B1, cf11);
                }

                // ---- update: all 64 lanes compute identical h0,h1 ----
                float2 gl = Gl2[jj][16 * w + l15];
                float f0 = (c10[0] + c10[1]) + c40f[u] + gl.x;
                float f1 = (c11[0] + c11[1]) + c41f[u] + gl.y;
                float h0 = 0.9f * hp0 + 0.1f * fast_tanh(f0);
                float h1 = 0.9f * hp1 + 0.1f * fast_tanh(f1);
                hp0 = h0; hp1 = h1;
                const int wsl = t & 7;
                unsigned short hh0 = f2bf(h0), hh1 = f2bf(h1);
                unsigned short lo0 = f2bf(h0 - bf2f(hh0)), lo1 = f2bf(h1 - bf2f(hh1));
                unsigned short v0 = varw ? lo0 : hh0;
                unsigned short v1 = varw ? lo1 : hh1;
                unsigned short wv = (quad & 1) ? v1 : v0;
                hwb[(size_t)wsl * HWSLOT + hw_off] = wv;
                if (quad < 2) hob[jj][s_w] = (quad & 1) ? h1 : h0;
                __syncthreads();
            }
        }

        // ---- flush hob -> out, coalesced float4 ----
        {
            const int nf4 = (tend - t0) * (RR / 4);
            const float4* src = (const float4*)&hob[0][0];
            float4* dst = (float4*)(outw + (size_t)t0 * RR);
#pragma unroll
            for (int it = 0; it < 3; ++it) {
                int idx = it * NTHR + tid;
                if (idx < nf4) dst[idx] = src[idx];
            }
        }
    }
}

extern "C" void kernel_launch(void* const* d_in, const int* in_sizes, int n_in,
                              void* d_out, int out_size, void* d_ws, size_t ws_size,
                              hipStream_t stream) {
    const float* x    = (const float*)d_in[0];   // (64, 2048, 1)
    const float* W_in = (const float*)d_in[1];   // (256, 1)
    const float* W_fb = (const float*)d_in[2];   // (5, 256, 256)
    const float* tapw = (const float*)d_in[3];   // (5,)
    const float* bias = (const float*)d_in[4];   // (256,)
    float* out = (float*)d_out;                  // (64, 2048, 256)
    unsigned short* bp = (unsigned short*)d_ws;  // 640 KB packed bf16 B-fragments

    pack_weights<<<160, 256, 0, stream>>>(W_fb, tapw, bp);
    reservoir_mfma<<<BB, NTHR, 0, stream>>>(x, W_in, bias, bp, out);
}